// Round 10
// baseline (419.762 us; speedup 1.0000x reference)
//
#include <hip/hip_runtime.h>
#include <hip/hip_bf16.h>
#include <math.h>

// ---------------------------------------------------------------------------
// GATv2 3-layer GNN. CSR-by-dst padded to 4-edge batches (self-loop folded
// in); f16 MFMA GEMMs; BN/ReLU/residual fused into attention.
// R7: LDS-histogram counting sort (contention-free), perm by row length.
// R9 measured: 4-dst/wave attn REGRESSED (occ 64->40%, latency-bound at
// VALU 38%) -> revert to 2-dst/wave (25K waves) but keep sorted pairing.
// scatter_gemm0 exposed at 73.7us with VALU 1.2% -> cursor was 16/line;
// pad cursor to one cache line per dst (line-serialized atomics theory).
// ---------------------------------------------------------------------------

using h16     = _Float16;
using half2v  = __attribute__((ext_vector_type(2))) h16;
using half4v  = __attribute__((ext_vector_type(4))) h16;
using half8   = __attribute__((ext_vector_type(8))) h16;
using floatx2 = __attribute__((ext_vector_type(2))) float;
using floatx4 = __attribute__((ext_vector_type(4))) float;

__device__ __forceinline__ float lrelu(float x) { return x > 0.f ? x : 0.2f * x; }

__device__ __forceinline__ half2v shfl_xor_h2(half2v v, int mask) {
    float f = __builtin_bit_cast(float, v);
    f = __shfl_xor(f, mask, 64);
    return __builtin_bit_cast(half2v, f);
}

// ---------------- CSR build ----------------
// padded row length = ceil((deg+1)/4)*4  (self-loop + pads)
__global__ __launch_bounds__(256) void scan_blk(const int* __restrict__ deg,
                                                int* __restrict__ rowstart,
                                                int* __restrict__ bsum,
                                                int* __restrict__ bins, int N) {
    __shared__ int lhist[32];
    if (threadIdx.x < 32) lhist[threadIdx.x] = 0;
    __syncthreads();
    int t = blockIdx.x * 256 + threadIdx.x;
    int lane = threadIdx.x & 63, wid = threadIdx.x >> 6;
    int v = 0;
    if (t < N) {
        v = (deg[t] + 4) & ~3;
        atomicAdd(&lhist[min(v >> 2, 31)], 1);   // LDS histogram
    }
    int x = v;
#pragma unroll
    for (int off = 1; off < 64; off <<= 1) {
        int y = __shfl_up(x, off, 64);
        if (lane >= off) x += y;
    }
    __shared__ int wsum[4];
    if (lane == 63) wsum[wid] = x;
    __syncthreads();
    int add = 0;
#pragma unroll
    for (int w = 0; w < 4; ++w) if (w < wid) add += wsum[w];
    int incl = x + add;
    if (t < N) rowstart[t] = incl - v;
    if (threadIdx.x == 255) bsum[blockIdx.x] = incl;
    // flush block histogram: <=32 global atomics per block
    if (threadIdx.x < 32) {
        int c = lhist[threadIdx.x];
        if (c) atomicAdd(&bins[threadIdx.x], c);
    }
}

__global__ __launch_bounds__(256) void scan_off(int* __restrict__ bsum, int NB,
                                                const int* __restrict__ bins,
                                                int* __restrict__ bincur) {
    int t = threadIdx.x;
    int lane = t & 63, wid = t >> 6;
    int v = (t < NB) ? bsum[t] : 0;
    int x = v;
#pragma unroll
    for (int off = 1; off < 64; off <<= 1) {
        int y = __shfl_up(x, off, 64);
        if (lane >= off) x += y;
    }
    __shared__ int wsum[4];
    if (lane == 63) wsum[wid] = x;
    __syncthreads();
    int add = 0;
#pragma unroll
    for (int w = 0; w < 4; ++w) if (w < wid) add += wsum[w];
    if (t < NB) bsum[t] = x + add - v;
    // exclusive scan of the 32 degree-bins (lanes 0..31 of wave 0)
    if (t < 32) {
        int b = bins[t];
        int xb = b;
#pragma unroll
        for (int off2 = 1; off2 < 32; off2 <<= 1) {
            int y = __shfl_up(xb, off2, 64);
            if (t >= off2) xb += y;
        }
        bincur[t] = xb - b;
    }
}

// cursor is padded: one 64B cache line (16 ints) per dst.
__global__ __launch_bounds__(256) void add_off(
        const int* __restrict__ bsum, const int* __restrict__ deg,
        int* __restrict__ rowstart, int* __restrict__ cursor,
        int* __restrict__ csr_src,
        int* __restrict__ bincur, int* __restrict__ perm, int N) {
    __shared__ int lhist[32], lbase[32], lcur[32];
    if (threadIdx.x < 32) { lhist[threadIdx.x] = 0; lcur[threadIdx.x] = 0; }
    __syncthreads();
    int t = blockIdx.x * 256 + threadIdx.x;
    int b = 0;
    bool valid = t < N;
    if (valid) {
        int r = rowstart[t] + bsum[blockIdx.x];
        rowstart[t] = r;
        cursor[(size_t)t * 16] = r;              // padded: line per dst
        int dg = deg[t];
        int npad = (dg + 4) & ~3;
        for (int k = dg; k < npad; ++k) csr_src[r + k] = t;
        b = min(npad >> 2, 31);
        atomicAdd(&lhist[b], 1);                 // LDS count
    }
    __syncthreads();
    if (threadIdx.x < 32) {
        int c = lhist[threadIdx.x];
        lbase[threadIdx.x] = c ? atomicAdd(&bincur[threadIdx.x], c) : 0;  // reserve
    }
    __syncthreads();
    if (valid) {
        int rank = atomicAdd(&lcur[b], 1);       // LDS rank within block+bin
        perm[lbase[b] + rank] = t;
    }
}

// ------- weight packing + x conversion + dst histogram (one launch) -------
__device__ __forceinline__ void pack_one(const float* __restrict__ W,
                                         h16* __restrict__ Wp,
                                         int t, int K, int NC) {
    int j = t & 7;
    int l = (t >> 3) & 63;
    int rest = t >> 9;
    int NT = NC >> 4;
    int nt = rest % NT;
    int kc = rest / NT;
    int row = kc * 32 + (l >> 4) * 8 + j;
    int col = nt * 16 + (l & 15);
    Wp[t] = (h16)W[(size_t)row * NC + col];
}

__global__ void pack_all(const float* __restrict__ W_in,
                         const float* __restrict__ Wl0, const float* __restrict__ Wr0,
                         const float* __restrict__ Wl1, const float* __restrict__ Wr1,
                         h16* __restrict__ P_in,
                         h16* __restrict__ P_l0, h16* __restrict__ P_r0,
                         h16* __restrict__ P_l1, h16* __restrict__ P_r1,
                         const float4* __restrict__ x, half4v* __restrict__ xh, int n4,
                         const int* __restrict__ ei, int E, int* __restrict__ deg) {
    int t = blockIdx.x * blockDim.x + threadIdx.x;
    if (t < 8192)        pack_one(W_in, P_in, t, 128, 64);
    else if (t < 24576)  pack_one(Wl0, P_l0, t - 8192, 64, 256);
    else if (t < 40960)  pack_one(Wr0, P_r0, t - 24576, 64, 256);
    else if (t < 106496) pack_one(Wl1, P_l1, t - 40960, 256, 256);
    else if (t < 172032) pack_one(Wr1, P_r1, t - 106496, 256, 256);
    else if (t < 172032 + n4) {
        int u = t - 172032;
        float4 v = x[u];
        half4v o = { (h16)v.x, (h16)v.y, (h16)v.z, (h16)v.w };
        xh[u] = o;
    } else {
        int u = t - 172032 - n4;
        if (u < E) atomicAdd(&deg[ei[E + u]], 1);   // dst histogram (deg memset'd)
    }
}

// --------- MFMA GEMM body, double-buffered LDS staging of W ----------------
template<int KC, int NT, bool RELU>
__device__ __forceinline__ void gemm_body(const h16* __restrict__ Xh,
                                          const h16* __restrict__ Wp,
                                          const float* __restrict__ bias,
                                          h16* __restrict__ outp, int M, int bx) {
    constexpr int K = KC * 32;
    constexpr int ldo = NT * 16;
    constexpr int CHUNK8 = NT * 64;
    constexpr int PER_THR = CHUNK8 / 256;
    __shared__ half8 wbuf[2][CHUNK8];

    const half8* WG = (const half8*)Wp;
    const int tid = threadIdx.x;
    const int wid = tid >> 6, lane = tid & 63;
    const int quad = lane >> 4, li = lane & 15;
    const int r0 = bx * 64 + wid * 16;
    int arow = r0 + li; if (arow >= M) arow = M - 1;
    const half8* A8 = (const half8*)Xh + (size_t)arow * (K / 8) + quad;

    floatx4 acc[NT];
#pragma unroll
    for (int t = 0; t < NT; ++t) acc[t] = (floatx4){0.f, 0.f, 0.f, 0.f};

    half8 st[PER_THR];
#pragma unroll
    for (int i = 0; i < PER_THR; ++i) st[i] = WG[i * 256 + tid];
#pragma unroll
    for (int i = 0; i < PER_THR; ++i) wbuf[0][i * 256 + tid] = st[i];
    __syncthreads();

#pragma unroll
    for (int kc = 0; kc < KC; ++kc) {
        int cur = kc & 1;
        if (kc + 1 < KC) {
#pragma unroll
            for (int i = 0; i < PER_THR; ++i)
                st[i] = WG[(size_t)(kc + 1) * CHUNK8 + i * 256 + tid];
        }
        half8 a = A8[kc * 4];
#pragma unroll
        for (int nt = 0; nt < NT; ++nt) {
            half8 b = wbuf[cur][nt * 64 + lane];
            acc[nt] = __builtin_amdgcn_mfma_f32_16x16x32_f16(a, b, acc[nt], 0, 0, 0);
        }
        if (kc + 1 < KC) {
#pragma unroll
            for (int i = 0; i < PER_THR; ++i) wbuf[cur ^ 1][i * 256 + tid] = st[i];
        }
        __syncthreads();
    }

#pragma unroll
    for (int nt = 0; nt < NT; ++nt) {
#pragma unroll
        for (int reg = 0; reg < 4; ++reg) {
            int rr = r0 + quad * 4 + reg;
            if (rr >= M) continue;
            float v = acc[nt][reg];
            if (RELU) v = fmaxf(v + bias[nt * 16 + li], 0.f);
            outp[(size_t)rr * ldo + nt * 16 + li] = (h16)v;
        }
    }
}

template<int KC, int NT, bool RELU, bool DUAL>
__global__ __launch_bounds__(256) void gemm_lds(
        const h16* __restrict__ Xh,
        const h16* __restrict__ Wp0, const h16* __restrict__ Wp1,
        const float* __restrict__ bias,
        h16* __restrict__ out0, h16* __restrict__ out1, int M) {
    const h16* Wp = (DUAL && blockIdx.y) ? Wp1 : Wp0;
    h16* outp = (DUAL && blockIdx.y) ? out1 : out0;
    gemm_body<KC, NT, RELU>(Xh, Wp, bias, outp, M, blockIdx.x);
}

// ---- scatter_src co-launched with the h0 GEMM (independent work) ----------
// cursor padded: 16-int stride per dst (kills same-line atomic serialization)
__global__ __launch_bounds__(256) void scatter_gemm0(
        const int* __restrict__ ei, int E,
        int* __restrict__ cursor, int* __restrict__ csr_src, int GS,
        const h16* __restrict__ xh, const h16* __restrict__ Wp_in,
        const float* __restrict__ b_in, h16* __restrict__ H0h, int M) {
    if ((int)blockIdx.x < GS) {
        int e = blockIdx.x * 256 + threadIdx.x;
        if (e < E) {
            int d = ei[E + e];
            int pos = atomicAdd(&cursor[(size_t)d * 16], 1);
            csr_src[pos] = ei[e];
        }
    } else {
        gemm_body<4, 4, true>(xh, Wp_in, b_in, H0h, M, blockIdx.x - GS);
    }
}

// ---- fused 4-head attention + BN + ReLU (+residual), 2 dst/wave, f16 -----
// 32 lanes per dst, 8 channels per lane (uint2 gathers). Head = 8 lanes ->
// 3-stage shfl reduce. perm pairs equal-length dsts (sorted) so npmax ==
// npad almost always. Pads masked via rem; clamped reloads are L1 hits.
__global__ void attn4_bn(int N, const h16* __restrict__ XL,
                         const h16* __restrict__ XR,
                         const float* __restrict__ att,
                         const int* __restrict__ perm,
                         const int* __restrict__ rowstart, const int* __restrict__ deg,
                         const int* __restrict__ csr_src,
                         const float* __restrict__ gamma, const float* __restrict__ beta,
                         const float* __restrict__ mean, const float* __restrict__ var,
                         const float* __restrict__ bias, const h16* __restrict__ resid,
                         h16* __restrict__ outb) {
    int wv = blockIdx.x * (blockDim.x >> 6) + (threadIdx.x >> 6);
    if (wv * 2 >= N) return;
    int lane = threadIdx.x & 63;
    int sl   = lane & 31;                 // lane within the 32-lane half
    int idx  = wv * 2 + (lane >> 5);      // sorted-dst slot
    bool dvalid = idx < N;
    int dh = perm[dvalid ? idx : (N - 1)];

    int start = rowstart[dh];
    int dg    = deg[dh];
    int nreal = dg + 1;                   // self-loop included in CSR
    int npad  = (dg + 4) & ~3;            // row padded to multiple of 4
    int npmax = max(npad, __shfl_xor(npad, 32, 64));

    union H8 { uint4 u; half2v h[4]; };
    H8 bv, wt;
    bv.u = *(const uint4*)(XR + (size_t)dh * 256 + sl * 8);
    {
        const float* ar = att + (sl >> 3) * 64 + (sl & 7) * 8;
        float4 wa = *(const float4*)ar;
        float4 wb = *(const float4*)(ar + 4);
        wt.h[0] = half2v{(h16)wa.x, (h16)wa.y};
        wt.h[1] = half2v{(h16)wa.z, (h16)wa.w};
        wt.h[2] = half2v{(h16)wb.x, (h16)wb.y};
        wt.h[3] = half2v{(h16)wb.z, (h16)wb.w};
    }
    const h16 k02 = (h16)0.2f;
    const uint2* XLv = (const uint2*)XL;   // 8B units; row stride = 32 units

    auto ep = [&](const H8& x) -> h16 {
        half2v q{(h16)0, (h16)0};
#pragma unroll
        for (int j = 0; j < 4; ++j) {
            half2v e  = x.h[j] + bv.h[j];
            half2v lr = __builtin_elementwise_max(e, e * k02);
            q += lr * wt.h[j];
        }
        return q.x + q.y;
    };

    float l = 0.f;
    half2v acc[4] = {half2v{(h16)0,(h16)0}, half2v{(h16)0,(h16)0},
                     half2v{(h16)0,(h16)0}, half2v{(h16)0,(h16)0}};

    int4 iv = *(const int4*)(csr_src + start);    // npad >= 4 always
    for (int i = 0; i < npmax; i += 4) {
        int4 cur = iv;
        if (i + 4 < npmax) {
            int nxt = min(i + 4, npad - 4);       // clamp: finished half re-reads
            iv = *(const int4*)(csr_src + start + nxt);
        }
        H8 x0, x1, x2, x3;
        x0.u = __builtin_bit_cast(uint4, (uint2[2]){
            XLv[(size_t)(unsigned)cur.x * 32 + sl], uint2{0,0}});
        // (use direct uint2 loads; see below)
        uint2 v0 = XLv[(size_t)(unsigned)cur.x * 32 + sl];
        uint2 v1 = XLv[(size_t)(unsigned)cur.y * 32 + sl];
        uint2 v2 = XLv[(size_t)(unsigned)cur.z * 32 + sl];
        uint2 v3 = XLv[(size_t)(unsigned)cur.w * 32 + sl];
        H8 y0, y1, y2, y3;
        y0.u = uint4{v0.x, v0.y, 0, 0};
        y1.u = uint4{v1.x, v1.y, 0, 0};
        y2.u = uint4{v2.x, v2.y, 0, 0};
        y3.u = uint4{v3.x, v3.y, 0, 0};
        // only h[0..1] valid (4 bf16 ch x 2) -- wait: 8 ch = 16B. Use uint2 pairs:
        // Each lane covers 8 channels = 16 bytes = uint4. Load as two uint2? No:
        // row stride 256 h16 = 512B = 32 uint4 units. Keep uint4 loads:
        (void)y0; (void)y1; (void)y2; (void)y3; (void)x0;
        const uint4* XL4 = (const uint4*)XL;
        H8 z0, z1, z2, z3;
        z0.u = XL4[(size_t)(unsigned)cur.x * 32 + sl];
        z1.u = XL4[(size_t)(unsigned)cur.y * 32 + sl];
        z2.u = XL4[(size_t)(unsigned)cur.z * 32 + sl];
        z3.u = XL4[(size_t)(unsigned)cur.w * 32 + sl];
        half2v p01 = { ep(z0), ep(z1) };
        half2v p23 = { ep(z2), ep(z3) };
#pragma unroll
        for (int s = 1; s < 8; s <<= 1) {         // 8 lanes per head
            p01 += shfl_xor_h2(p01, s);
            p23 += shfl_xor_h2(p23, s);
        }
        int rem = nreal - i;
        float e0 = (rem > 0) ? __expf((float)p01.x) : 0.f;
        float e1 = (rem > 1) ? __expf((float)p01.y) : 0.f;
        float e2 = (rem > 2) ? __expf((float)p23.x) : 0.f;
        float e3 = (rem > 3) ? __expf((float)p23.y) : 0.f;
        l += (e0 + e1) + (e2 + e3);
        h16 h0 = (h16)e0, h1 = (h16)e1, h2 = (h16)e2, h3 = (h16)e3;
        half2v eb0{h0,h0}, eb1{h1,h1}, eb2{h2,h2}, eb3{h3,h3};
#pragma unroll
        for (int j = 0; j < 4; ++j) {
            acc[j] += eb0 * z0.h[j];
            acc[j] += eb1 * z1.h[j];
            acc[j] += eb2 * z2.h[j];
            acc[j] += eb3 * z3.h[j];
        }
    }

    float inv = 1.f / l;
    float oc[8];
#pragma unroll
    for (int j = 0; j < 4; ++j) { oc[2*j] = (float)acc[j].x; oc[2*j+1] = (float)acc[j].y; }
    const float4* g4  = (const float4*)gamma;
    const float4* be4 = (const float4*)beta;
    const float4* mu4 = (const float4*)mean;
    const float4* va4 = (const float4*)var;
    const float4* bi4 = (const float4*)bias;
    float o[8];
#pragma unroll
    for (int q = 0; q < 2; ++q) {
        float4 g  = g4[sl*2+q],  bb = be4[sl*2+q], mu = mu4[sl*2+q];
        float4 va = va4[sl*2+q], bi = bi4[sl*2+q];
        float s0 = g.x * rsqrtf(va.x + 1e-5f);
        float s1 = g.y * rsqrtf(va.y + 1e-5f);
        float s2 = g.z * rsqrtf(va.z + 1e-5f);
        float s3 = g.w * rsqrtf(va.w + 1e-5f);
        o[q*4+0] = fmaxf(oc[q*4+0]*inv*s0 + (bi.x-mu.x)*s0 + bb.x, 0.f);
        o[q*4+1] = fmaxf(oc[q*4+1]*inv*s1 + (bi.y-mu.y)*s1 + bb.y, 0.f);
        o[q*4+2] = fmaxf(oc[q*4+2]*inv*s2 + (bi.z-mu.z)*s2 + bb.z, 0.f);
        o[q*4+3] = fmaxf(oc[q*4+3]*inv*s3 + (bi.w-mu.w)*s3 + bb.w, 0.f);
    }
    if (resid) {
        H8 rv; rv.u = *(const uint4*)(resid + (size_t)dh * 256 + sl * 8);
#pragma unroll
        for (int j = 0; j < 4; ++j) {
            o[2*j]   += (float)rv.h[j].x;
            o[2*j+1] += (float)rv.h[j].y;
        }
    }
    if (dvalid) {
        H8 ov;
#pragma unroll
        for (int j = 0; j < 4; ++j) ov.h[j] = half2v{(h16)o[2*j], (h16)o[2*j+1]};
        *(uint4*)(outb + (size_t)dh * 256 + sl * 8) = ov.u;
    }
}

// ---- layer 2 projections from f16 input: 16 lanes/node, K=256 ----
__global__ void gemm2_wave(const h16* __restrict__ X, const float* __restrict__ Wl,
                           const float* __restrict__ Wr, float* __restrict__ xl2,
                           float* __restrict__ xr2, int N) {
    int t = blockIdx.x * blockDim.x + threadIdx.x;
    int n = t >> 4;
    int sl = t & 15;
    if (n >= N) return;
    const half4v* Xr = (const half4v*)(X + (size_t)n * 256);
    const float4* Wl4 = (const float4*)Wl;
    const float4* Wr4 = (const float4*)Wr;
    float l0 = 0.f, l1 = 0.f, r0 = 0.f, r1 = 0.f;
#pragma unroll
    for (int j = 0; j < 4; ++j) {
        int idx = sl + j * 16;
        half4v xh = Xr[idx];
        float4 xv = { (float)xh.x, (float)xh.y, (float)xh.z, (float)xh.w };
        float4 wa = Wl4[idx * 2];
        float4 wb = Wl4[idx * 2 + 1];
        l0 += xv.x * wa.x + xv.y * wa.z + xv.z * wb.x + xv.w * wb.z;
        l1 += xv.x * wa.y + xv.y * wa.w + xv.z * wb.y + xv.w * wb.w;
        wa = Wr4[idx * 2]; wb = Wr4[idx * 2 + 1];
        r0 += xv.x * wa.x + xv.y * wa.z + xv.z * wb.x + xv.w * wb.z;
        r1 += xv.x * wa.y + xv.y * wa.w + xv.z * wb.y + xv.w * wb.w;
    }
#pragma unroll
    for (int off = 1; off < 16; off <<= 1) {
        l0 += __shfl_xor(l0, off, 64);
        l1 += __shfl_xor(l1, off, 64);
        r0 += __shfl_xor(r0, off, 64);
        r1 += __shfl_xor(r1, off, 64);
    }
    if (sl == 0) {
        xl2[n * 2] = l0; xl2[n * 2 + 1] = l1;
        xr2[n * 2] = r0; xr2[n * 2 + 1] = r1;
    }
}

// ---- fused layer-2 attention (1 head, C=2) + log_softmax, 16 lanes/dst ----
__global__ void attn1_16(int N, const float* __restrict__ xl2, const float* __restrict__ xr2,
                         const float* __restrict__ att, const float* __restrict__ bias,
                         const int* __restrict__ rowstart, const int* __restrict__ deg,
                         const int* __restrict__ csr_src, float* __restrict__ out) {
    int t = blockIdx.x * blockDim.x + threadIdx.x;
    int d = t >> 4, sl = t & 15;
    if (d >= N) return;
    float a0 = att[0], a1 = att[1];
    float2 xr = ((const float2*)xr2)[d];
    float b0 = xr.x, b1 = xr.y;
    int st = rowstart[d];
    int nreal = deg[d] + 1;
    int npad  = (deg[d] + 4) & ~3;
    float l = 0.f, ac0 = 0.f, ac1 = 0.f;
    for (int i = sl; i < npad; i += 16) {
        int s = csr_src[st + i];
        float2 xv = ((const float2*)xl2)[s];
        float q = lrelu(xv.x + b0) * a0 + lrelu(xv.y + b1) * a1;
        float e = (i < nreal) ? __expf(q) : 0.f;
        l += e; ac0 += e * xv.x; ac1 += e * xv.y;
    }
#pragma unroll
    for (int off = 1; off < 16; off <<= 1) {
        l   += __shfl_xor(l, off, 64);
        ac0 += __shfl_xor(ac0, off, 64);
        ac1 += __shfl_xor(ac1, off, 64);
    }
    if (sl == 0) {
        float inv = 1.f / l;
        float v0 = ac0 * inv + bias[0];
        float v1 = ac1 * inv + bias[1];
        float mx = fmaxf(v0, v1);
        float lse = mx + logf(__expf(v0 - mx) + __expf(v1 - mx));
        out[d * 2] = v0 - lse;
        out[d * 2 + 1] = v1 - lse;
    }
}

extern "C" void kernel_launch(void* const* d_in, const int* in_sizes, int n_in,
                              void* d_out, int out_size, void* d_ws, size_t ws_size,
                              hipStream_t stream) {
    const float* x        = (const float*)d_in[0];
    const int*   ei       = (const int*)  d_in[1];
    const float* W_in     = (const float*)d_in[2];
    const float* b_in     = (const float*)d_in[3];
    const float* Wl0      = (const float*)d_in[4];
    const float* Wr0      = (const float*)d_in[5];
    const float* att0     = (const float*)d_in[6];
    const float* bias0    = (const float*)d_in[7];
    const float* Wl1      = (const float*)d_in[8];
    const float* Wr1      = (const float*)d_in[9];
    const float* att1     = (const float*)d_in[10];
    const float* bias1    = (const float*)d_in[11];
    const float* Wl2      = (const float*)d_in[12];
    const float* Wr2      = (const float*)d_in[13];
    const float* att2     = (const float*)d_in[14];
    const float* bias2    = (const float*)d_in[15];
    const float* bn_gamma = (const float*)d_in[16];
    const float* bn_beta  = (const float*)d_in[17];
    const float* bn_mean  = (const float*)d_in[18];
    const float* bn_var   = (const float*)d_in[19];

    const int N  = in_sizes[0] / 128;
    const int E  = in_sizes[1] / 2;
    const int NB = (N + 255) / 256;

    float* ws = (float*)d_ws;
    size_t off = 0;
    float* XL2  = ws + off; off += (size_t)N * 2;
    float* XR2  = ws + off; off += (size_t)N * 2;
    h16* Ah   = (h16*)(ws + off); off += (size_t)N * 128;  // f16 xl tables [N,256]
    h16* Bh   = (h16*)(ws + off); off += (size_t)N * 128;  // f16 xr tables [N,256]
    h16* Ch   = (h16*)(ws + off); off += (size_t)N * 128;  // f16 layer0 out / residual
    h16* Dh   = (h16*)(ws + off); off += (size_t)N * 128;  // f16 layer1 out
    h16* H0h  = (h16*)(ws + off); off += (size_t)N * 32;   // f16 h0 [N,64]
    h16* xh   = (h16*)(ws + off); off += (size_t)N * 64;   // f16 x  [N,128]
    h16* Wp_in = (h16*)(ws + off); off += 4096;    // 128*64
    h16* Wp_l0 = (h16*)(ws + off); off += 8192;    // 64*256
    h16* Wp_r0 = (h16*)(ws + off); off += 8192;
    h16* Wp_l1 = (h16*)(ws + off); off += 32768;   // 256*256
    h16* Wp_r1 = (h16*)(ws + off); off += 32768;
    int* ip = (int*)(ws + off);
    int* deg      = ip;              ip += N;
    int* bins     = ip;              ip += 32;      // adjacent to deg: one memset
    int* bincur   = ip;              ip += 32;
    int* rowstart = ip;              ip += N;
    int* bsum     = ip;              ip += NB;
    int* perm     = ip;              ip += N;
    int* cursor   = ip;              ip += (size_t)N * 16;  // padded: 64B/dst
    int* csr_src  = ip;              ip += E + 4 * N + 64;  // padded CSR

    // deg + bins zero (bincur written by scan_off)
    hipMemsetAsync(deg, 0, (size_t)(N + 32) * sizeof(int), stream);

    // ---- weight packing + x conversion + dst histogram (one launch) ----
    const int PACK_T = 172032 + N * 32 + E;
    pack_all<<<(PACK_T + 255) / 256, 256, 0, stream>>>(
        W_in, Wl0, Wr0, Wl1, Wr1, Wp_in, Wp_l0, Wp_r0, Wp_l1, Wp_r1,
        (const float4*)x, (half4v*)xh, N * 32, ei, E, deg);

    // ---- CSR build (parallel scan, padded rows incl. self-loop) ----
    scan_blk<<<NB, 256, 0, stream>>>(deg, rowstart, bsum, bins, N);
    scan_off<<<1, 256, 0, stream>>>(bsum, NB, bins, bincur);
    add_off<<<NB, 256, 0, stream>>>(bsum, deg, rowstart, cursor, csr_src,
                                    bincur, perm, N);

    const int GBM = (N + 63) / 64;
    const int GS  = (E + 255) / 256;

    // scatter edges into CSR  ||  h0 = relu(x @ W_in + b_in) -> f16
    scatter_gemm0<<<GS + GBM, 256, 0, stream>>>(ei, E, cursor, csr_src, GS,
                                                xh, Wp_in, b_in, H0h, N);

    // -------- layer 0 --------
    gemm_lds<2, 16, false, true><<<dim3(GBM, 2), 256, 0, stream>>>(
        H0h, Wp_l0, Wp_r0, nullptr, Ah, Bh, N);
    attn4_bn<<<(N + 7) / 8, 256, 0, stream>>>(N, Ah, Bh, att0, perm,
                                              rowstart, deg, csr_src,
                                              bn_gamma, bn_beta, bn_mean, bn_var,
                                              bias0, nullptr, Ch);

    // -------- layer 1 (residual) --------
    gemm_lds<8, 16, false, true><<<dim3(GBM, 2), 256, 0, stream>>>(
        Ch, Wp_l1, Wp_r1, nullptr, Ah, Bh, N);
    attn4_bn<<<(N + 7) / 8, 256, 0, stream>>>(N, Ah, Bh, att1, perm,
                                              rowstart, deg, csr_src,
                                              bn_gamma + 256, bn_beta + 256, bn_mean + 256,
                                              bn_var + 256, bias1, Ch, Dh);

    // -------- layer 2 (1 head, C=2) + log_softmax --------
    gemm2_wave<<<(N * 16 + 255) / 256, 256, 0, stream>>>(Dh, Wl2, Wr2, XL2, XR2, N);
    attn1_16<<<(N * 16 + 255) / 256, 256, 0, stream>>>(N, XL2, XR2, att2, bias2,
                                                       rowstart, deg, csr_src, (float*)d_out);
}

// Round 11
// 397.051 us; speedup vs baseline: 1.0572x; 1.0572x over previous
//
#include <hip/hip_runtime.h>
#include <hip/hip_bf16.h>
#include <math.h>

// ---------------------------------------------------------------------------
// GATv2 3-layer GNN. CSR-by-dst padded to 4-edge batches (self-loop folded
// in); f16 MFMA GEMMs; BN/ReLU/residual fused into attention.
// R10 measured: (a) cursor line-padding NULL (scatter still 72us, VALU 1.3%,
// WRITE 60MB) -> real cause is return-value atomics at the far coherence
// point (XCD L2s non-coherent): serial chain per thread. Fix: 4 edges per
// thread = 4 independent atomic chains (ILP latency hiding).
// (b) sorted-perm attn pairing NULL-negative (71 vs 68us, occ 53 vs 64) ->
// revert to plain consecutive 2-dst/wave attn (R5's 68us point); delete
// the counting-sort machinery entirely.
// ---------------------------------------------------------------------------

using h16     = _Float16;
using half2v  = __attribute__((ext_vector_type(2))) h16;
using half4v  = __attribute__((ext_vector_type(4))) h16;
using half8   = __attribute__((ext_vector_type(8))) h16;
using floatx2 = __attribute__((ext_vector_type(2))) float;
using floatx4 = __attribute__((ext_vector_type(4))) float;

__device__ __forceinline__ float lrelu(float x) { return x > 0.f ? x : 0.2f * x; }

__device__ __forceinline__ half2v shfl_xor_h2(half2v v, int mask) {
    float f = __builtin_bit_cast(float, v);
    f = __shfl_xor(f, mask, 64);
    return __builtin_bit_cast(half2v, f);
}

// ---------------- CSR build ----------------
// padded row length = ceil((deg+1)/4)*4  (self-loop + pads)
__global__ __launch_bounds__(256) void scan_blk(const int* __restrict__ deg,
                                                int* __restrict__ rowstart,
                                                int* __restrict__ bsum, int N) {
    int t = blockIdx.x * 256 + threadIdx.x;
    int lane = threadIdx.x & 63, wid = threadIdx.x >> 6;
    int v = (t < N) ? ((deg[t] + 4) & ~3) : 0;
    int x = v;
#pragma unroll
    for (int off = 1; off < 64; off <<= 1) {
        int y = __shfl_up(x, off, 64);
        if (lane >= off) x += y;
    }
    __shared__ int wsum[4];
    if (lane == 63) wsum[wid] = x;
    __syncthreads();
    int add = 0;
#pragma unroll
    for (int w = 0; w < 4; ++w) if (w < wid) add += wsum[w];
    int incl = x + add;
    if (t < N) rowstart[t] = incl - v;
    if (threadIdx.x == 255) bsum[blockIdx.x] = incl;
}

__global__ __launch_bounds__(256) void scan_off(int* __restrict__ bsum, int NB) {
    int t = threadIdx.x;
    int lane = t & 63, wid = t >> 6;
    int v = (t < NB) ? bsum[t] : 0;
    int x = v;
#pragma unroll
    for (int off = 1; off < 64; off <<= 1) {
        int y = __shfl_up(x, off, 64);
        if (lane >= off) x += y;
    }
    __shared__ int wsum[4];
    if (lane == 63) wsum[wid] = x;
    __syncthreads();
    int add = 0;
#pragma unroll
    for (int w = 0; w < 4; ++w) if (w < wid) add += wsum[w];
    if (t < NB) bsum[t] = x + add - v;
}

__global__ void add_off(const int* __restrict__ bsum, const int* __restrict__ deg,
                        int* __restrict__ rowstart, int* __restrict__ cursor,
                        int* __restrict__ csr_src, int N) {
    int t = blockIdx.x * 256 + threadIdx.x;
    if (t >= N) return;
    int r = rowstart[t] + bsum[blockIdx.x];
    rowstart[t] = r;
    cursor[t] = r;
    int dg = deg[t];
    int npad = (dg + 4) & ~3;
    for (int k = dg; k < npad; ++k) csr_src[r + k] = t;
}

// ------- weight packing + x conversion + dst histogram (one launch) -------
__device__ __forceinline__ void pack_one(const float* __restrict__ W,
                                         h16* __restrict__ Wp,
                                         int t, int K, int NC) {
    int j = t & 7;
    int l = (t >> 3) & 63;
    int rest = t >> 9;
    int NT = NC >> 4;
    int nt = rest % NT;
    int kc = rest / NT;
    int row = kc * 32 + (l >> 4) * 8 + j;
    int col = nt * 16 + (l & 15);
    Wp[t] = (h16)W[(size_t)row * NC + col];
}

__global__ void pack_all(const float* __restrict__ W_in,
                         const float* __restrict__ Wl0, const float* __restrict__ Wr0,
                         const float* __restrict__ Wl1, const float* __restrict__ Wr1,
                         h16* __restrict__ P_in,
                         h16* __restrict__ P_l0, h16* __restrict__ P_r0,
                         h16* __restrict__ P_l1, h16* __restrict__ P_r1,
                         const float4* __restrict__ x, half4v* __restrict__ xh, int n4,
                         const int* __restrict__ ei, int E, int* __restrict__ deg) {
    int t = blockIdx.x * blockDim.x + threadIdx.x;
    if (t < 8192)        pack_one(W_in, P_in, t, 128, 64);
    else if (t < 24576)  pack_one(Wl0, P_l0, t - 8192, 64, 256);
    else if (t < 40960)  pack_one(Wr0, P_r0, t - 24576, 64, 256);
    else if (t < 106496) pack_one(Wl1, P_l1, t - 40960, 256, 256);
    else if (t < 172032) pack_one(Wr1, P_r1, t - 106496, 256, 256);
    else if (t < 172032 + n4) {
        int u = t - 172032;
        float4 v = x[u];
        half4v o = { (h16)v.x, (h16)v.y, (h16)v.z, (h16)v.w };
        xh[u] = o;
    } else {
        int u = t - 172032 - n4;
        if (u < E) atomicAdd(&deg[ei[E + u]], 1);   // no-return atomic: throughput-ok
    }
}

// --------- MFMA GEMM body, double-buffered LDS staging of W ----------------
template<int KC, int NT, bool RELU>
__device__ __forceinline__ void gemm_body(const h16* __restrict__ Xh,
                                          const h16* __restrict__ Wp,
                                          const float* __restrict__ bias,
                                          h16* __restrict__ outp, int M, int bx) {
    constexpr int K = KC * 32;
    constexpr int ldo = NT * 16;
    constexpr int CHUNK8 = NT * 64;
    constexpr int PER_THR = CHUNK8 / 256;
    __shared__ half8 wbuf[2][CHUNK8];

    const half8* WG = (const half8*)Wp;
    const int tid = threadIdx.x;
    const int wid = tid >> 6, lane = tid & 63;
    const int quad = lane >> 4, li = lane & 15;
    const int r0 = bx * 64 + wid * 16;
    int arow = r0 + li; if (arow >= M) arow = M - 1;
    const half8* A8 = (const half8*)Xh + (size_t)arow * (K / 8) + quad;

    floatx4 acc[NT];
#pragma unroll
    for (int t = 0; t < NT; ++t) acc[t] = (floatx4){0.f, 0.f, 0.f, 0.f};

    half8 st[PER_THR];
#pragma unroll
    for (int i = 0; i < PER_THR; ++i) st[i] = WG[i * 256 + tid];
#pragma unroll
    for (int i = 0; i < PER_THR; ++i) wbuf[0][i * 256 + tid] = st[i];
    __syncthreads();

#pragma unroll
    for (int kc = 0; kc < KC; ++kc) {
        int cur = kc & 1;
        if (kc + 1 < KC) {
#pragma unroll
            for (int i = 0; i < PER_THR; ++i)
                st[i] = WG[(size_t)(kc + 1) * CHUNK8 + i * 256 + tid];
        }
        half8 a = A8[kc * 4];
#pragma unroll
        for (int nt = 0; nt < NT; ++nt) {
            half8 b = wbuf[cur][nt * 64 + lane];
            acc[nt] = __builtin_amdgcn_mfma_f32_16x16x32_f16(a, b, acc[nt], 0, 0, 0);
        }
        if (kc + 1 < KC) {
#pragma unroll
            for (int i = 0; i < PER_THR; ++i) wbuf[cur ^ 1][i * 256 + tid] = st[i];
        }
        __syncthreads();
    }

#pragma unroll
    for (int nt = 0; nt < NT; ++nt) {
#pragma unroll
        for (int reg = 0; reg < 4; ++reg) {
            int rr = r0 + quad * 4 + reg;
            if (rr >= M) continue;
            float v = acc[nt][reg];
            if (RELU) v = fmaxf(v + bias[nt * 16 + li], 0.f);
            outp[(size_t)rr * ldo + nt * 16 + li] = (h16)v;
        }
    }
}

template<int KC, int NT, bool RELU, bool DUAL>
__global__ __launch_bounds__(256) void gemm_lds(
        const h16* __restrict__ Xh,
        const h16* __restrict__ Wp0, const h16* __restrict__ Wp1,
        const float* __restrict__ bias,
        h16* __restrict__ out0, h16* __restrict__ out1, int M) {
    const h16* Wp = (DUAL && blockIdx.y) ? Wp1 : Wp0;
    h16* outp = (DUAL && blockIdx.y) ? out1 : out0;
    gemm_body<KC, NT, RELU>(Xh, Wp, bias, outp, M, blockIdx.x);
}

// ---- scatter_src (4 edges/thread, independent atomic chains) || h0 GEMM ---
__global__ __launch_bounds__(256) void scatter_gemm0(
        const int* __restrict__ ei, int E,
        int* __restrict__ cursor, int* __restrict__ csr_src, int GS,
        const h16* __restrict__ xh, const h16* __restrict__ Wp_in,
        const float* __restrict__ b_in, h16* __restrict__ H0h, int M) {
    if ((int)blockIdx.x < GS) {
        int base = blockIdx.x * 1024 + threadIdx.x;
        int e0 = base, e1 = base + 256, e2 = base + 512, e3 = base + 768;
        // 4 independent load->atomic->store chains in flight per thread
        int d0 = (e0 < E) ? ei[E + e0] : 0;
        int d1 = (e1 < E) ? ei[E + e1] : 0;
        int d2 = (e2 < E) ? ei[E + e2] : 0;
        int d3 = (e3 < E) ? ei[E + e3] : 0;
        int p0 = (e0 < E) ? atomicAdd(&cursor[d0], 1) : 0;
        int p1 = (e1 < E) ? atomicAdd(&cursor[d1], 1) : 0;
        int p2 = (e2 < E) ? atomicAdd(&cursor[d2], 1) : 0;
        int p3 = (e3 < E) ? atomicAdd(&cursor[d3], 1) : 0;
        int s0 = (e0 < E) ? ei[e0] : 0;
        int s1 = (e1 < E) ? ei[e1] : 0;
        int s2 = (e2 < E) ? ei[e2] : 0;
        int s3 = (e3 < E) ? ei[e3] : 0;
        if (e0 < E) csr_src[p0] = s0;
        if (e1 < E) csr_src[p1] = s1;
        if (e2 < E) csr_src[p2] = s2;
        if (e3 < E) csr_src[p3] = s3;
    } else {
        gemm_body<4, 4, true>(xh, Wp_in, b_in, H0h, M, blockIdx.x - GS);
    }
}

// ---- fused 4-head attention + BN + ReLU (+residual), 2 dst/wave, f16 -----
// 32 lanes per dst, 8 channels per lane (b128 gathers). Head = 8 lanes ->
// 3-stage shfl reduce. Consecutive dsts (no perm). Pair tail masked via
// rem<=0; clamped index quads re-read the last valid quad (L1 hit).
__global__ void attn4_bn(int N, const h16* __restrict__ XL,
                         const h16* __restrict__ XR,
                         const float* __restrict__ att,
                         const int* __restrict__ rowstart, const int* __restrict__ deg,
                         const int* __restrict__ csr_src,
                         const float* __restrict__ gamma, const float* __restrict__ beta,
                         const float* __restrict__ mean, const float* __restrict__ var,
                         const float* __restrict__ bias, const h16* __restrict__ resid,
                         h16* __restrict__ outb) {
    int wv = blockIdx.x * (blockDim.x >> 6) + (threadIdx.x >> 6);
    int d0 = wv * 2;
    if (d0 >= N) return;
    int lane = threadIdx.x & 63;
    int sl   = lane & 31;                 // lane within the 32-lane half
    int dh   = d0 + (lane >> 5);          // this half's dst
    bool dvalid = dh < N;
    int dr = dvalid ? dh : d0;

    int start = rowstart[dr];
    int dg    = deg[dr];
    int nreal = dg + 1;                   // self-loop included in CSR
    int npad  = (dg + 4) & ~3;            // row padded to multiple of 4
    int npmax = max(npad, __shfl_xor(npad, 32, 64));

    union H8 { uint4 u; half2v h[4]; };
    H8 bv, wt;
    bv.u = *(const uint4*)(XR + (size_t)dr * 256 + sl * 8);
    {
        const float* ar = att + (sl >> 3) * 64 + (sl & 7) * 8;
        float4 wa = *(const float4*)ar;
        float4 wb = *(const float4*)(ar + 4);
        wt.h[0] = half2v{(h16)wa.x, (h16)wa.y};
        wt.h[1] = half2v{(h16)wa.z, (h16)wa.w};
        wt.h[2] = half2v{(h16)wb.x, (h16)wb.y};
        wt.h[3] = half2v{(h16)wb.z, (h16)wb.w};
    }
    const h16 k02 = (h16)0.2f;
    const uint4* XLv = (const uint4*)XL;   // 16B units; row stride = 32 units

    auto ep = [&](const H8& x) -> h16 {
        half2v q{(h16)0, (h16)0};
#pragma unroll
        for (int j = 0; j < 4; ++j) {
            half2v e  = x.h[j] + bv.h[j];
            half2v lr = __builtin_elementwise_max(e, e * k02);
            q += lr * wt.h[j];
        }
        return q.x + q.y;
    };

    float l = 0.f;
    half2v acc[4] = {half2v{(h16)0,(h16)0}, half2v{(h16)0,(h16)0},
                     half2v{(h16)0,(h16)0}, half2v{(h16)0,(h16)0}};

    int4 iv = *(const int4*)(csr_src + start);    // npad >= 4 always
    for (int i = 0; i < npmax; i += 4) {
        int4 cur = iv;
        if (i + 4 < npmax) {
            int nxt = min(i + 4, npad - 4);       // clamp: finished half re-reads
            iv = *(const int4*)(csr_src + start + nxt);
        }
        H8 x0, x1, x2, x3;
        x0.u = XLv[(size_t)(unsigned)cur.x * 32 + sl];
        x1.u = XLv[(size_t)(unsigned)cur.y * 32 + sl];
        x2.u = XLv[(size_t)(unsigned)cur.z * 32 + sl];
        x3.u = XLv[(size_t)(unsigned)cur.w * 32 + sl];
        half2v p01 = { ep(x0), ep(x1) };
        half2v p23 = { ep(x2), ep(x3) };
#pragma unroll
        for (int s = 1; s < 8; s <<= 1) {         // 8 lanes per head
            p01 += shfl_xor_h2(p01, s);
            p23 += shfl_xor_h2(p23, s);
        }
        int rem = nreal - i;
        float e0 = (rem > 0) ? __expf((float)p01.x) : 0.f;
        float e1 = (rem > 1) ? __expf((float)p01.y) : 0.f;
        float e2 = (rem > 2) ? __expf((float)p23.x) : 0.f;
        float e3 = (rem > 3) ? __expf((float)p23.y) : 0.f;
        l += (e0 + e1) + (e2 + e3);
        h16 h0 = (h16)e0, h1 = (h16)e1, h2 = (h16)e2, h3 = (h16)e3;
        half2v eb0{h0,h0}, eb1{h1,h1}, eb2{h2,h2}, eb3{h3,h3};
#pragma unroll
        for (int j = 0; j < 4; ++j) {
            acc[j] += eb0 * x0.h[j];
            acc[j] += eb1 * x1.h[j];
            acc[j] += eb2 * x2.h[j];
            acc[j] += eb3 * x3.h[j];
        }
    }

    float inv = 1.f / l;
    float oc[8];
#pragma unroll
    for (int j = 0; j < 4; ++j) { oc[2*j] = (float)acc[j].x; oc[2*j+1] = (float)acc[j].y; }
    const float4* g4  = (const float4*)gamma;
    const float4* be4 = (const float4*)beta;
    const float4* mu4 = (const float4*)mean;
    const float4* va4 = (const float4*)var;
    const float4* bi4 = (const float4*)bias;
    float o[8];
#pragma unroll
    for (int q = 0; q < 2; ++q) {
        float4 g  = g4[sl*2+q],  bb = be4[sl*2+q], mu = mu4[sl*2+q];
        float4 va = va4[sl*2+q], bi = bi4[sl*2+q];
        float s0 = g.x * rsqrtf(va.x + 1e-5f);
        float s1 = g.y * rsqrtf(va.y + 1e-5f);
        float s2 = g.z * rsqrtf(va.z + 1e-5f);
        float s3 = g.w * rsqrtf(va.w + 1e-5f);
        o[q*4+0] = fmaxf(oc[q*4+0]*inv*s0 + (bi.x-mu.x)*s0 + bb.x, 0.f);
        o[q*4+1] = fmaxf(oc[q*4+1]*inv*s1 + (bi.y-mu.y)*s1 + bb.y, 0.f);
        o[q*4+2] = fmaxf(oc[q*4+2]*inv*s2 + (bi.z-mu.z)*s2 + bb.z, 0.f);
        o[q*4+3] = fmaxf(oc[q*4+3]*inv*s3 + (bi.w-mu.w)*s3 + bb.w, 0.f);
    }
    if (resid) {
        H8 rv; rv.u = *(const uint4*)(resid + (size_t)dr * 256 + sl * 8);
#pragma unroll
        for (int j = 0; j < 4; ++j) {
            o[2*j]   += (float)rv.h[j].x;
            o[2*j+1] += (float)rv.h[j].y;
        }
    }
    if (dvalid) {
        H8 ov;
#pragma unroll
        for (int j = 0; j < 4; ++j) ov.h[j] = half2v{(h16)o[2*j], (h16)o[2*j+1]};
        *(uint4*)(outb + (size_t)dh * 256 + sl * 8) = ov.u;
    }
}

// ---- layer 2 projections from f16 input: 16 lanes/node, K=256 ----
__global__ void gemm2_wave(const h16* __restrict__ X, const float* __restrict__ Wl,
                           const float* __restrict__ Wr, float* __restrict__ xl2,
                           float* __restrict__ xr2, int N) {
    int t = blockIdx.x * blockDim.x + threadIdx.x;
    int n = t >> 4;
    int sl = t & 15;
    if (n >= N) return;
    const half4v* Xr = (const half4v*)(X + (size_t)n * 256);
    const float4* Wl4 = (const float4*)Wl;
    const float4* Wr4 = (const float4*)Wr;
    float l0 = 0.f, l1 = 0.f, r0 = 0.f, r1 = 0.f;
#pragma unroll
    for (int j = 0; j < 4; ++j) {
        int idx = sl + j * 16;
        half4v xh = Xr[idx];
        float4 xv = { (float)xh.x, (float)xh.y, (float)xh.z, (float)xh.w };
        float4 wa = Wl4[idx * 2];
        float4 wb = Wl4[idx * 2 + 1];
        l0 += xv.x * wa.x + xv.y * wa.z + xv.z * wb.x + xv.w * wb.z;
        l1 += xv.x * wa.y + xv.y * wa.w + xv.z * wb.y + xv.w * wb.w;
        wa = Wr4[idx * 2]; wb = Wr4[idx * 2 + 1];
        r0 += xv.x * wa.x + xv.y * wa.z + xv.z * wb.x + xv.w * wb.z;
        r1 += xv.x * wa.y + xv.y * wa.w + xv.z * wb.y + xv.w * wb.w;
    }
#pragma unroll
    for (int off = 1; off < 16; off <<= 1) {
        l0 += __shfl_xor(l0, off, 64);
        l1 += __shfl_xor(l1, off, 64);
        r0 += __shfl_xor(r0, off, 64);
        r1 += __shfl_xor(r1, off, 64);
    }
    if (sl == 0) {
        xl2[n * 2] = l0; xl2[n * 2 + 1] = l1;
        xr2[n * 2] = r0; xr2[n * 2 + 1] = r1;
    }
}

// ---- fused layer-2 attention (1 head, C=2) + log_softmax, 16 lanes/dst ----
__global__ void attn1_16(int N, const float* __restrict__ xl2, const float* __restrict__ xr2,
                         const float* __restrict__ att, const float* __restrict__ bias,
                         const int* __restrict__ rowstart, const int* __restrict__ deg,
                         const int* __restrict__ csr_src, float* __restrict__ out) {
    int t = blockIdx.x * blockDim.x + threadIdx.x;
    int d = t >> 4, sl = t & 15;
    if (d >= N) return;
    float a0 = att[0], a1 = att[1];
    float2 xr = ((const float2*)xr2)[d];
    float b0 = xr.x, b1 = xr.y;
    int st = rowstart[d];
    int nreal = deg[d] + 1;
    int npad  = (deg[d] + 4) & ~3;
    float l = 0.f, ac0 = 0.f, ac1 = 0.f;
    for (int i = sl; i < npad; i += 16) {
        int s = csr_src[st + i];
        float2 xv = ((const float2*)xl2)[s];
        float q = lrelu(xv.x + b0) * a0 + lrelu(xv.y + b1) * a1;
        float e = (i < nreal) ? __expf(q) : 0.f;
        l += e; ac0 += e * xv.x; ac1 += e * xv.y;
    }
#pragma unroll
    for (int off = 1; off < 16; off <<= 1) {
        l   += __shfl_xor(l, off, 64);
        ac0 += __shfl_xor(ac0, off, 64);
        ac1 += __shfl_xor(ac1, off, 64);
    }
    if (sl == 0) {
        float inv = 1.f / l;
        float v0 = ac0 * inv + bias[0];
        float v1 = ac1 * inv + bias[1];
        float mx = fmaxf(v0, v1);
        float lse = mx + logf(__expf(v0 - mx) + __expf(v1 - mx));
        out[d * 2] = v0 - lse;
        out[d * 2 + 1] = v1 - lse;
    }
}

extern "C" void kernel_launch(void* const* d_in, const int* in_sizes, int n_in,
                              void* d_out, int out_size, void* d_ws, size_t ws_size,
                              hipStream_t stream) {
    const float* x        = (const float*)d_in[0];
    const int*   ei       = (const int*)  d_in[1];
    const float* W_in     = (const float*)d_in[2];
    const float* b_in     = (const float*)d_in[3];
    const float* Wl0      = (const float*)d_in[4];
    const float* Wr0      = (const float*)d_in[5];
    const float* att0     = (const float*)d_in[6];
    const float* bias0    = (const float*)d_in[7];
    const float* Wl1      = (const float*)d_in[8];
    const float* Wr1      = (const float*)d_in[9];
    const float* att1     = (const float*)d_in[10];
    const float* bias1    = (const float*)d_in[11];
    const float* Wl2      = (const float*)d_in[12];
    const float* Wr2      = (const float*)d_in[13];
    const float* att2     = (const float*)d_in[14];
    const float* bias2    = (const float*)d_in[15];
    const float* bn_gamma = (const float*)d_in[16];
    const float* bn_beta  = (const float*)d_in[17];
    const float* bn_mean  = (const float*)d_in[18];
    const float* bn_var   = (const float*)d_in[19];

    const int N  = in_sizes[0] / 128;
    const int E  = in_sizes[1] / 2;
    const int NB = (N + 255) / 256;

    float* ws = (float*)d_ws;
    size_t off = 0;
    float* XL2  = ws + off; off += (size_t)N * 2;
    float* XR2  = ws + off; off += (size_t)N * 2;
    h16* Ah   = (h16*)(ws + off); off += (size_t)N * 128;  // f16 xl tables [N,256]
    h16* Bh   = (h16*)(ws + off); off += (size_t)N * 128;  // f16 xr tables [N,256]
    h16* Ch   = (h16*)(ws + off); off += (size_t)N * 128;  // f16 layer0 out / residual
    h16* Dh   = (h16*)(ws + off); off += (size_t)N * 128;  // f16 layer1 out
    h16* H0h  = (h16*)(ws + off); off += (size_t)N * 32;   // f16 h0 [N,64]
    h16* xh   = (h16*)(ws + off); off += (size_t)N * 64;   // f16 x  [N,128]
    h16* Wp_in = (h16*)(ws + off); off += 4096;    // 128*64
    h16* Wp_l0 = (h16*)(ws + off); off += 8192;    // 64*256
    h16* Wp_r0 = (h16*)(ws + off); off += 8192;
    h16* Wp_l1 = (h16*)(ws + off); off += 32768;   // 256*256
    h16* Wp_r1 = (h16*)(ws + off); off += 32768;
    int* ip = (int*)(ws + off);
    int* deg      = ip;              ip += N;
    int* rowstart = ip;              ip += N;
    int* cursor   = ip;              ip += N;
    int* bsum     = ip;              ip += NB;
    int* csr_src  = ip;              ip += E + 4 * N + 64;  // padded CSR

    // deg zero
    hipMemsetAsync(deg, 0, (size_t)N * sizeof(int), stream);

    // ---- weight packing + x conversion + dst histogram (one launch) ----
    const int PACK_T = 172032 + N * 32 + E;
    pack_all<<<(PACK_T + 255) / 256, 256, 0, stream>>>(
        W_in, Wl0, Wr0, Wl1, Wr1, Wp_in, Wp_l0, Wp_r0, Wp_l1, Wp_r1,
        (const float4*)x, (half4v*)xh, N * 32, ei, E, deg);

    // ---- CSR build (parallel scan, padded rows incl. self-loop) ----
    scan_blk<<<NB, 256, 0, stream>>>(deg, rowstart, bsum, N);
    scan_off<<<1, 256, 0, stream>>>(bsum, NB);
    add_off<<<NB, 256, 0, stream>>>(bsum, deg, rowstart, cursor, csr_src, N);

    const int GBM = (N + 63) / 64;
    const int GS  = (E + 1023) / 1024;   // 4 edges per thread

    // scatter edges into CSR  ||  h0 = relu(x @ W_in + b_in) -> f16
    scatter_gemm0<<<GS + GBM, 256, 0, stream>>>(ei, E, cursor, csr_src, GS,
                                                xh, Wp_in, b_in, H0h, N);

    // -------- layer 0 --------
    gemm_lds<2, 16, false, true><<<dim3(GBM, 2), 256, 0, stream>>>(
        H0h, Wp_l0, Wp_r0, nullptr, Ah, Bh, N);
    attn4_bn<<<(N + 7) / 8, 256, 0, stream>>>(N, Ah, Bh, att0,
                                              rowstart, deg, csr_src,
                                              bn_gamma, bn_beta, bn_mean, bn_var,
                                              bias0, nullptr, Ch);

    // -------- layer 1 (residual) --------
    gemm_lds<8, 16, false, true><<<dim3(GBM, 2), 256, 0, stream>>>(
        Ch, Wp_l1, Wp_r1, nullptr, Ah, Bh, N);
    attn4_bn<<<(N + 7) / 8, 256, 0, stream>>>(N, Ah, Bh, att1,
                                              rowstart, deg, csr_src,
                                              bn_gamma + 256, bn_beta + 256, bn_mean + 256,
                                              bn_var + 256, bias1, Ch, Dh);

    // -------- layer 2 (1 head, C=2) + log_softmax --------
    gemm2_wave<<<(N * 16 + 255) / 256, 256, 0, stream>>>(Dh, Wl2, Wr2, XL2, XR2, N);
    attn1_16<<<(N * 16 + 255) / 256, 256, 0, stream>>>(N, XL2, XR2, att2, bias2,
                                                       rowstart, deg, csr_src, (float*)d_out);
}